// Round 15
// baseline (558.796 us; speedup 1.0000x reference)
//
#include <hip/hip_runtime.h>
#include <hip/hip_bf16.h>
#include <stdint.h>

// ---------------- problem constants ----------------
#define N_TOK 8192
#define DIM   1024
#define FF    4096
#define NEXP  8
#define MAXT1 72     // 256-row tiles; 72 = 8 XCDs * 9
#define WN4   (NEXP * FF * DIM / 4)
#define NGRP  2048

// ---------------- workspace layout (bytes) ----------------
#define OFF_COUNTS 0ull
#define OFF_NT     64ull
#define OFF_T256   4096ull            // 72*16
#define OFF_IDX    16384ull
#define OFF_GATE   278528ull
#define OFF_BH     540672ull
#define OFF_SEL    606208ull
#define OFF_XB     1048576ull
#define OFF_H      17825792ull        // 18432*4096*2 = 150,994,944 (256-padded rows)
#define OFF_WB     168820736ull
#define OFF_W2B    235929600ull
#define NEED       235929600ull
#define NEED2      303038464ull

typedef __attribute__((ext_vector_type(8))) short s16x8;
typedef __attribute__((ext_vector_type(4))) float f32x4;

__device__ __forceinline__ unsigned short f2bf(float f) {
  union { float f; unsigned int u; } v; v.f = f;
  unsigned int u = v.u;
  unsigned int r = (u + 0x7FFFu + ((u >> 16) & 1u)) >> 16;  // RNE
  return (unsigned short)r;
}
__device__ __forceinline__ ushort4 bf4(float4 f) {
  ushort4 u;
  u.x = f2bf(f.x); u.y = f2bf(f.y); u.z = f2bf(f.z); u.w = f2bf(f.w);
  return u;
}

// gelu: 0.5*x*(1+erf(x/sqrt2)), erf via A&S 7.1.26 (|err|<1.5e-7)
__device__ __forceinline__ float gelu_f(float x) {
  float s = x * 0.70710678118654752f;
  float a = fabsf(s);
  float t = 1.0f / fmaf(0.3275911f, a, 1.0f);
  float p = t * fmaf(t, fmaf(t, fmaf(t, fmaf(t, 1.061405429f, -1.453152027f),
                                     1.421413741f), -0.284496736f), 0.254829592f);
  float e = __expf(-a * a);
  float erf_a = 1.0f - p * e;
  float erf_s = (s >= 0.0f) ? erf_a : -erf_a;
  return 0.5f * x * (1.0f + erf_s);
}

__device__ __forceinline__ void load_lds16(const void* g, void* l) {
  __builtin_amdgcn_global_load_lds(
      (const __attribute__((address_space(1))) unsigned int*)g,
      (__attribute__((address_space(3))) unsigned int*)l, 16, 0, 0);
}

// ---------------- f32 -> bf16 bulk convert (serial fallback) ----------------
__global__ __launch_bounds__(256) void cvt_f32_bf16(const float4* __restrict__ in,
                                                    ushort4* __restrict__ out, int n4) {
  int i = blockIdx.x * 256 + threadIdx.x;
  int stride = gridDim.x * 256;
  for (; i < n4; i += stride) out[i] = bf4(in[i]);
}

// ---------------- K1: router (8/9) + fat w1-cvt blocks (1/9) -----------------
__global__ __launch_bounds__(256) void router_cvt(
    const float* __restrict__ x, const float* __restrict__ rw,
    int* __restrict__ bh, int4* __restrict__ sel,
    unsigned short* __restrict__ xb,
    const float4* __restrict__ w1f, ushort4* __restrict__ w1o) {
  const int bid = blockIdx.x;
  if ((bid + 1) % 9 == 0) {
    const int c = (bid + 1) / 9 - 1;
    const int STR = 256 * 256;
    int i = c * 256 + (int)threadIdx.x;
    for (; i + 3 * STR < WN4; i += 4 * STR) {
      float4 f0 = w1f[i], f1 = w1f[i + STR], f2 = w1f[i + 2 * STR], f3 = w1f[i + 3 * STR];
      w1o[i] = bf4(f0); w1o[i + STR] = bf4(f1);
      w1o[i + 2 * STR] = bf4(f2); w1o[i + 3 * STR] = bf4(f3);
    }
    for (; i < WN4; i += STR) w1o[i] = bf4(w1f[i]);
    return;
  }
  const int tb = bid - (bid + 1) / 9;
  int wid = threadIdx.x >> 6;
  int lane = threadIdx.x & 63;
  int token = tb * 4 + wid;

  __shared__ int lh[NEXP];
  if (threadIdx.x < NEXP) lh[threadIdx.x] = 0;
  __syncthreads();

  const float4* xr = (const float4*)(x + (size_t)token * DIM);
  ushort4* xw = (ushort4*)(xb + (size_t)token * DIM);
  float p[NEXP];
#pragma unroll
  for (int e = 0; e < NEXP; ++e) p[e] = 0.f;
#pragma unroll
  for (int c = 0; c < 4; ++c) {
    float4 xv = xr[c * 64 + lane];
    xw[c * 64 + lane] = bf4(xv);
#pragma unroll
    for (int e = 0; e < NEXP; ++e) {
      float4 wv = ((const float4*)(rw + (size_t)e * DIM))[c * 64 + lane];
      p[e] += xv.x * wv.x + xv.y * wv.y + xv.z * wv.z + xv.w * wv.w;
    }
  }
#pragma unroll
  for (int e = 0; e < NEXP; ++e) {
    float v = p[e];
#pragma unroll
    for (int off = 32; off > 0; off >>= 1) v += __shfl_xor(v, off, 64);
    p[e] = v;
  }
  if (lane == 0) {
    int e0 = 0; float v0 = p[0];
#pragma unroll
    for (int e = 1; e < NEXP; ++e) if (p[e] > v0) { v0 = p[e]; e0 = e; }
    int e1 = (e0 == 0) ? 1 : 0; float v1 = -3.4e38f;
#pragma unroll
    for (int e = 0; e < NEXP; ++e) if (e != e0 && p[e] > v1) { v1 = p[e]; e1 = e; }
    float ex = __expf(v1 - v0);
    float g0 = 1.0f / (1.0f + ex);
    float g1 = ex / (1.0f + ex);
    atomicAdd(&lh[e0], 1);
    atomicAdd(&lh[e1], 1);
    sel[token] = make_int4(e0, e1, __float_as_int(g0), __float_as_int(g1));
  }
  __syncthreads();
  if (threadIdx.x < NEXP) bh[tb * NEXP + threadIdx.x] = lh[threadIdx.x];
}

// ---------------- K2: scan + 256-tile table + scatter + out-zero -------------
__global__ __launch_bounds__(1024) void scan_scatter(
    const int* __restrict__ bh, const int4* __restrict__ sel,
    int* __restrict__ counts, int4* __restrict__ t256, int* __restrict__ nt,
    int* __restrict__ idx_list, float* __restrict__ gate_list,
    float4* __restrict__ outz) {
  if (blockIdx.x != 0) {
    const int zb = blockIdx.x - 1;
    const int n4 = N_TOK * DIM / 4;
    const float4 z = make_float4(0.f, 0.f, 0.f, 0.f);
    for (int i = zb * 1024 + threadIdx.x; i < n4; i += 255 * 1024) outz[i] = z;
    return;
  }
  extern __shared__ int s_bb[];
  __shared__ int s_cnt[NEXP];
  const int tid = threadIdx.x;
  const int wave = tid >> 6, lane = tid & 63;

  if (wave < NEXP) {
    const int e = wave;
    int running = 0;
    for (int c = 0; c < NGRP / 64; ++c) {
      const int b = c * 64 + lane;
      int v = bh[b * NEXP + e];
      int incl = v;
#pragma unroll
      for (int off = 1; off < 64; off <<= 1) {
        int y = __shfl_up(incl, off, 64);
        if (lane >= off) incl += y;
      }
      s_bb[b * NEXP + e] = running + (incl - v);
      running += __shfl(incl, 63, 64);
    }
    if (lane == 0) { s_cnt[e] = running; counts[e] = running; }
  }
  __syncthreads();

  if (tid == 0) {
    int a = 0, g = 0;
#pragma unroll
    for (int e = 0; e < NEXP; ++e) {
      int c = s_cnt[e];
      int n1 = (c + 255) >> 8;
      for (int i = 0; i < n1; ++i) t256[a++] = make_int4(e, i << 8, g + (i << 8), 0);
      g += n1 << 8;
    }
    nt[0] = a;
  }

  for (int g = tid; g < NGRP; g += 1024) {
    int4 s0 = sel[g * 4 + 0], s1 = sel[g * 4 + 1];
    int4 s2 = sel[g * 4 + 2], s3 = sel[g * 4 + 3];
#define EMIT(i, sv, r0, r1)                                              \
    {                                                                     \
      int p0 = s_bb[g * NEXP + sv.x] + (r0);                              \
      int p1 = s_bb[g * NEXP + sv.y] + (r1);                              \
      idx_list[sv.x * N_TOK + p0] = g * 4 + i;                            \
      gate_list[sv.x * N_TOK + p0] = __int_as_float(sv.z);                \
      idx_list[sv.y * N_TOK + p1] = g * 4 + i;                            \
      gate_list[sv.y * N_TOK + p1] = __int_as_float(sv.w);                \
    }
    EMIT(0, s0, 0, 0);
    EMIT(1, s1, (s0.x == s1.x) + (s0.y == s1.x), (s0.x == s1.y) + (s0.y == s1.y));
    EMIT(2, s2, (s0.x == s2.x) + (s0.y == s2.x) + (s1.x == s2.x) + (s1.y == s2.x),
                (s0.x == s2.y) + (s0.y == s2.y) + (s1.x == s2.y) + (s1.y == s2.y));
    EMIT(3, s3, (s0.x == s3.x) + (s0.y == s3.x) + (s1.x == s3.x) + (s1.y == s3.x) +
                (s2.x == s3.x) + (s2.y == s3.x),
                (s0.x == s3.y) + (s0.y == s3.y) + (s1.x == s3.y) + (s1.y == s3.y) +
                (s2.x == s3.y) + (s2.y == s3.y));
#undef EMIT
  }
}

// ---------------- grouped GEMM: 256x128 tile, BK=64, 8 waves, single buffer --
// THIS ROUND: tile aspect 256x128 (was 128x128) cuts total LDS-staged bytes
// ~23% per GEMM (B-panel staging halves: #row-tiles 136->72) while keeping the
// r13-PROVEN inner loop and the occupancy that makes it work: wave-out 64x64
// (acc 64 VGPR, no cliff), 48 KiB LDS -> 2 blocks/CU at 512 thr. 14-round
// invariant: all schedule variants pin at staged-bytes / ~10 TB/s; this lowers
// the numerator instead of fighting the schedule.
// Skeleton: {stage; sync; ds_read+MFMA; sync} per K-step (co-residency hides
// latency, m114). L2-aware chunked XCD mapping (r8). Source-pre-swizzled
// 16B-slot XOR (r3: 0 conflicts). FUSE (GEMM1): every 9th per-XCD slot is a
// fat w2-cvt block (~11% of slots) drafting on idle HBM bandwidth (r11).
// EPI==1: H[gbase+r] = gelu(A_gathered @ W^T) (bf16).
// EPI==2: atomicAdd(Out[token], gate * (H @ W^T)).
template <int KDIM, int EPI, int TPX, int CW, bool FUSE>
__global__ __launch_bounds__(512, 2) void moe_g(
    const unsigned short* __restrict__ Abase, const unsigned short* __restrict__ Bb,
    unsigned short* __restrict__ Hout, float* __restrict__ Out,
    const int* __restrict__ idx_list, const float* __restrict__ gate_list,
    const int* __restrict__ counts, const int4* __restrict__ table,
    const int* __restrict__ n_tiles,
    const float4* __restrict__ cvt_src, ushort4* __restrict__ cvt_dst) {
  int xcd, r0;
  if constexpr (FUSE) {
    const int bid = blockIdx.x;          // grid = 8 * 324
    xcd = bid & 7;
    const int r = bid >> 3;              // 0..323
    if (r % 9 == 8) {                    // 36 fat w2-cvt slots per XCD (288 total)
      const int c = xcd * 36 + r / 9;
      const int STR = 288 * 512;
      int i = c * 512 + (int)threadIdx.x;
      for (; i + 3 * STR < WN4; i += 4 * STR) {
        float4 f0 = cvt_src[i], f1 = cvt_src[i + STR];
        float4 f2 = cvt_src[i + 2 * STR], f3 = cvt_src[i + 3 * STR];
        cvt_dst[i] = bf4(f0); cvt_dst[i + STR] = bf4(f1);
        cvt_dst[i + 2 * STR] = bf4(f2); cvt_dst[i + 3 * STR] = bf4(f3);
      }
      for (; i < WN4; i += STR) cvt_dst[i] = bf4(cvt_src[i]);
      return;
    }
    r0 = r - r / 9;                      // 0..287
  } else {
    xcd = blockIdx.x & 7;
    r0 = blockIdx.x >> 3;
  }
  const int chunk = r0 / (TPX * CW), q = r0 % (TPX * CW);
  const int ty = xcd * TPX + q / CW;
  const int cx = chunk * CW + q % CW;
  if (ty >= *n_tiles) return;
  int4 te = table[ty];
  const int e = te.x, row_start = te.y, gbase = te.z;
  const int ce = counts[e];
  const int tid = threadIdx.x;
  const int wid = tid >> 6, lane = tid & 63;
  const int colT = cx * 128;

  __shared__ unsigned short Al[256 * 64];   // 32 KiB
  __shared__ unsigned short Bl[128 * 64];   // 16 KiB

  // staging: thread covers A rows {j*64+sr, j=0..3} and B rows {j*64+sr, j=0..1};
  // phys 16B-slot tid&7; global source col pre-swizzled by (row&7)=(sr&7).
  const int sr = tid >> 3;                  // 0..63
  const int scol = ((tid & 7) ^ (sr & 7)) * 8;
  size_t aoff[4], boff[2];
#pragma unroll
  for (int j = 0; j < 4; ++j) {
    int r = j * 64 + sr;
    if constexpr (EPI == 1) {
      int rl = row_start + r; if (rl >= ce) rl = ce - 1;   // clamp padded rows
      int tok = idx_list[e * N_TOK + rl];
      aoff[j] = ((size_t)tok * KDIM + scol) * 2;
    } else {
      aoff[j] = ((size_t)(gbase + r) * KDIM + scol) * 2;
    }
  }
#pragma unroll
  for (int j = 0; j < 2; ++j)
    boff[j] = ((size_t)e * FF * DIM + (size_t)(colT + j * 64 + sr) * KDIM + scol) * 2;
  const char* Ag = (const char*)Abase;
  const char* Bg = (const char*)Bb;
  const int NT = KDIM / 64;

  const int wr = wid >> 1, wc = wid & 1;    // 4x2 waves; wave out 64x64
  const int r16 = lane & 15, kg = lane >> 4;
  const int x7 = r16 & 7;

  f32x4 acc[4][4] = {};

  for (int t = 0; t < NT; ++t) {
    {
      char* da = (char*)Al + tid * 16;
      char* db = (char*)Bl + tid * 16;
      size_t ko = (size_t)t * 128;          // 64 elems * 2B
#pragma unroll
      for (int j = 0; j < 4; ++j) load_lds16(Ag + aoff[j] + ko, da + j * 8192);
#pragma unroll
      for (int j = 0; j < 2; ++j) load_lds16(Bg + boff[j] + ko, db + j * 8192);
    }
    __syncthreads();
    const char* Ap = (const char*)Al + (wr * 64 + r16) * 128;
    const char* Bp = (const char*)Bl + (wc * 64 + r16) * 128;
#pragma unroll
    for (int kf = 0; kf < 2; ++kf) {
      const int so = ((kf * 4 + kg) ^ x7) * 16;   // swizzled 16B-slot
      s16x8 a[4], b[4];
#pragma unroll
      for (int m = 0; m < 4; ++m) a[m] = *(const s16x8*)(Ap + m * 2048 + so);
#pragma unroll
      for (int n = 0; n < 4; ++n) b[n] = *(const s16x8*)(Bp + n * 2048 + so);
#pragma unroll
      for (int m = 0; m < 4; ++m)
#pragma unroll
        for (int n = 0; n < 4; ++n)
          acc[m][n] = __builtin_amdgcn_mfma_f32_16x16x32_bf16(a[m], b[n], acc[m][n], 0, 0, 0);
    }
    __syncthreads();
  }

  if constexpr (EPI == 1) {
#pragma unroll
    for (int m = 0; m < 4; ++m) {
      const int row_l = wr * 64 + m * 16 + kg * 4;
#pragma unroll
      for (int j = 0; j < 4; ++j) {
        size_t hrow = (size_t)(gbase + row_l + j) * FF + colT + wc * 64;
#pragma unroll
        for (int n = 0; n < 4; ++n)
          Hout[hrow + n * 16 + r16] = f2bf(gelu_f(acc[m][n][j]));
      }
    }
  } else {
#pragma unroll
    for (int m = 0; m < 4; ++m) {
      const int row_l = wr * 64 + m * 16 + kg * 4;
#pragma unroll
      for (int j = 0; j < 4; ++j) {
        int r = row_start + row_l + j;
        if (r < ce) {
          int tok = idx_list[e * N_TOK + r];
          float g = gate_list[e * N_TOK + r];
          float* orow = Out + (size_t)tok * DIM + colT + wc * 64;
#pragma unroll
          for (int n = 0; n < 4; ++n)
            atomicAdd(&orow[n * 16 + r16], acc[m][n][j] * g);
        }
      }
    }
  }
}

// ---------------- launch ----------------
extern "C" void kernel_launch(void* const* d_in, const int* in_sizes, int n_in,
                              void* d_out, int out_size, void* d_ws, size_t ws_size,
                              hipStream_t stream) {
  const float* x  = (const float*)d_in[0];
  const float* rw = (const float*)d_in[1];
  const float* w1 = (const float*)d_in[2];
  const float* w2 = (const float*)d_in[3];
  float* out = (float*)d_out;
  char* ws = (char*)d_ws;
  if (ws_size < NEED) return;
  const bool sep = ws_size >= NEED2;

  int*   counts    = (int*)(ws + OFF_COUNTS);
  int*   nt        = (int*)(ws + OFF_NT);
  int4*  t256      = (int4*)(ws + OFF_T256);
  int*   idx_list  = (int*)(ws + OFF_IDX);
  float* gate_list = (float*)(ws + OFF_GATE);
  int*   bh        = (int*)(ws + OFF_BH);
  int4*  sel       = (int4*)(ws + OFF_SEL);
  unsigned short* xb  = (unsigned short*)(ws + OFF_XB);
  unsigned short* h   = (unsigned short*)(ws + OFF_H);
  unsigned short* wb  = (unsigned short*)(ws + OFF_WB);
  unsigned short* w2b = (unsigned short*)(ws + OFF_W2B);

  hipFuncSetAttribute(reinterpret_cast<const void*>(&scan_scatter),
                      hipFuncAttributeMaxDynamicSharedMemorySize, 65536);

  // K1: router (2048) + fat w1-cvt (256), 8:1 interleave
  router_cvt<<<2304, 256, 0, stream>>>(x, rw, bh, sel, xb,
                                       (const float4*)w1, (ushort4*)wb);
  // K2: scan + table + scatter (block 0) + d_out zeroing (blocks 1..255)
  scan_scatter<<<256, 1024, 65536, stream>>>(bh, sel, counts, t256, nt,
                                             idx_list, gate_list, (float4*)out);

  if (sep) {
    // GEMM1: per-XCD 288 GEMM slots (9 ty x 32 cx, CW=8) + 36 cvt; grid 8*324
    moe_g<DIM, 1, 9, 8, true><<<8 * 324, 512, 0, stream>>>(
        xb, wb, h, nullptr, idx_list, gate_list, counts, t256, nt,
        (const float4*)w2, (ushort4*)w2b);
    // GEMM2: per-XCD 72 slots (9 ty x 8 cx, CW=4); grid 576
    moe_g<FF, 2, 9, 4, false><<<8 * 72, 512, 0, stream>>>(
        h, w2b, nullptr, out, idx_list, gate_list, counts, t256, nt,
        nullptr, nullptr);
  } else {
    moe_g<DIM, 1, 9, 8, false><<<8 * 288, 512, 0, stream>>>(
        xb, wb, h, nullptr, idx_list, gate_list, counts, t256, nt, nullptr, nullptr);
    cvt_f32_bf16<<<2048, 256, 0, stream>>>((const float4*)w2, (ushort4*)wb, WN4);
    moe_g<FF, 2, 9, 4, false><<<8 * 72, 512, 0, stream>>>(
        h, wb, nullptr, out, idx_list, gate_list, counts, t256, nt, nullptr, nullptr);
  }
}

// Round 16
// 504.384 us; speedup vs baseline: 1.1079x; 1.1079x over previous
//
#include <hip/hip_runtime.h>
#include <hip/hip_bf16.h>
#include <stdint.h>

// ---------------- problem constants ----------------
#define N_TOK 8192
#define DIM   1024
#define FF    4096
#define NEXP  8
#define MAXT  136    // 128-row tiles (GEMM2)
#define MAXT1 72     // 256-row tiles (GEMM1); per-XCD 9 ty
#define WN4   (NEXP * FF * DIM / 4)
#define NGRP  2048

// ---------------- workspace layout (bytes) ----------------
#define OFF_COUNTS 0ull
#define OFF_NT     64ull              // nt[0]=n256, nt[1]=n128
#define OFF_T256   4096ull            // 72*16
#define OFF_T128   8192ull            // 136*16
#define OFF_IDX    16384ull
#define OFF_GATE   278528ull
#define OFF_BH     540672ull
#define OFF_SEL    606208ull
#define OFF_XB     1048576ull
#define OFF_H      17825792ull        // 18432*4096*2 = 150,994,944 (256-padded rows)
#define OFF_WB     168820736ull
#define OFF_W2B    235929600ull
#define NEED       235929600ull
#define NEED2      303038464ull

typedef __attribute__((ext_vector_type(8))) short s16x8;
typedef __attribute__((ext_vector_type(4))) float f32x4;

__device__ __forceinline__ unsigned short f2bf(float f) {
  union { float f; unsigned int u; } v; v.f = f;
  unsigned int u = v.u;
  unsigned int r = (u + 0x7FFFu + ((u >> 16) & 1u)) >> 16;  // RNE
  return (unsigned short)r;
}
__device__ __forceinline__ ushort4 bf4(float4 f) {
  ushort4 u;
  u.x = f2bf(f.x); u.y = f2bf(f.y); u.z = f2bf(f.z); u.w = f2bf(f.w);
  return u;
}

// gelu: 0.5*x*(1+erf(x/sqrt2)), erf via A&S 7.1.26 (|err|<1.5e-7)
__device__ __forceinline__ float gelu_f(float x) {
  float s = x * 0.70710678118654752f;
  float a = fabsf(s);
  float t = 1.0f / fmaf(0.3275911f, a, 1.0f);
  float p = t * fmaf(t, fmaf(t, fmaf(t, fmaf(t, 1.061405429f, -1.453152027f),
                                     1.421413741f), -0.284496736f), 0.254829592f);
  float e = __expf(-a * a);
  float erf_a = 1.0f - p * e;
  float erf_s = (s >= 0.0f) ? erf_a : -erf_a;
  return 0.5f * x * (1.0f + erf_s);
}

__device__ __forceinline__ void load_lds16(const void* g, void* l) {
  __builtin_amdgcn_global_load_lds(
      (const __attribute__((address_space(1))) unsigned int*)g,
      (__attribute__((address_space(3))) unsigned int*)l, 16, 0, 0);
}

// ---------------- f32 -> bf16 bulk convert (serial fallback) ----------------
__global__ __launch_bounds__(256) void cvt_f32_bf16(const float4* __restrict__ in,
                                                    ushort4* __restrict__ out, int n4) {
  int i = blockIdx.x * 256 + threadIdx.x;
  int stride = gridDim.x * 256;
  for (; i < n4; i += stride) out[i] = bf4(in[i]);
}

// ---------------- K1: router (8/9) + fat w1-cvt blocks (1/9) -----------------
__global__ __launch_bounds__(256) void router_cvt(
    const float* __restrict__ x, const float* __restrict__ rw,
    int* __restrict__ bh, int4* __restrict__ sel,
    unsigned short* __restrict__ xb,
    const float4* __restrict__ w1f, ushort4* __restrict__ w1o) {
  const int bid = blockIdx.x;
  if ((bid + 1) % 9 == 0) {
    const int c = (bid + 1) / 9 - 1;
    const int STR = 256 * 256;
    int i = c * 256 + (int)threadIdx.x;
    for (; i + 3 * STR < WN4; i += 4 * STR) {
      float4 f0 = w1f[i], f1 = w1f[i + STR], f2 = w1f[i + 2 * STR], f3 = w1f[i + 3 * STR];
      w1o[i] = bf4(f0); w1o[i + STR] = bf4(f1);
      w1o[i + 2 * STR] = bf4(f2); w1o[i + 3 * STR] = bf4(f3);
    }
    for (; i < WN4; i += STR) w1o[i] = bf4(w1f[i]);
    return;
  }
  const int tb = bid - (bid + 1) / 9;
  int wid = threadIdx.x >> 6;
  int lane = threadIdx.x & 63;
  int token = tb * 4 + wid;

  __shared__ int lh[NEXP];
  if (threadIdx.x < NEXP) lh[threadIdx.x] = 0;
  __syncthreads();

  const float4* xr = (const float4*)(x + (size_t)token * DIM);
  ushort4* xw = (ushort4*)(xb + (size_t)token * DIM);
  float p[NEXP];
#pragma unroll
  for (int e = 0; e < NEXP; ++e) p[e] = 0.f;
#pragma unroll
  for (int c = 0; c < 4; ++c) {
    float4 xv = xr[c * 64 + lane];
    xw[c * 64 + lane] = bf4(xv);
#pragma unroll
    for (int e = 0; e < NEXP; ++e) {
      float4 wv = ((const float4*)(rw + (size_t)e * DIM))[c * 64 + lane];
      p[e] += xv.x * wv.x + xv.y * wv.y + xv.z * wv.z + xv.w * wv.w;
    }
  }
#pragma unroll
  for (int e = 0; e < NEXP; ++e) {
    float v = p[e];
#pragma unroll
    for (int off = 32; off > 0; off >>= 1) v += __shfl_xor(v, off, 64);
    p[e] = v;
  }
  if (lane == 0) {
    int e0 = 0; float v0 = p[0];
#pragma unroll
    for (int e = 1; e < NEXP; ++e) if (p[e] > v0) { v0 = p[e]; e0 = e; }
    int e1 = (e0 == 0) ? 1 : 0; float v1 = -3.4e38f;
#pragma unroll
    for (int e = 0; e < NEXP; ++e) if (e != e0 && p[e] > v1) { v1 = p[e]; e1 = e; }
    float ex = __expf(v1 - v0);
    float g0 = 1.0f / (1.0f + ex);
    float g1 = ex / (1.0f + ex);
    atomicAdd(&lh[e0], 1);
    atomicAdd(&lh[e1], 1);
    sel[token] = make_int4(e0, e1, __float_as_int(g0), __float_as_int(g1));
  }
  __syncthreads();
  if (threadIdx.x < NEXP) bh[tb * NEXP + threadIdx.x] = lh[threadIdx.x];
}

// ---------------- K2: scan + both tile tables + scatter + out-zero ----------
// gbase is 256-PADDED (shared h layout for both GEMMs).
__global__ __launch_bounds__(1024) void scan_scatter(
    const int* __restrict__ bh, const int4* __restrict__ sel,
    int* __restrict__ counts, int4* __restrict__ t256, int4* __restrict__ t128,
    int* __restrict__ nt, int* __restrict__ idx_list, float* __restrict__ gate_list,
    float4* __restrict__ outz) {
  if (blockIdx.x != 0) {
    const int zb = blockIdx.x - 1;
    const int n4 = N_TOK * DIM / 4;
    const float4 z = make_float4(0.f, 0.f, 0.f, 0.f);
    for (int i = zb * 1024 + threadIdx.x; i < n4; i += 255 * 1024) outz[i] = z;
    return;
  }
  extern __shared__ int s_bb[];
  __shared__ int s_cnt[NEXP];
  const int tid = threadIdx.x;
  const int wave = tid >> 6, lane = tid & 63;

  if (wave < NEXP) {
    const int e = wave;
    int running = 0;
    for (int c = 0; c < NGRP / 64; ++c) {
      const int b = c * 64 + lane;
      int v = bh[b * NEXP + e];
      int incl = v;
#pragma unroll
      for (int off = 1; off < 64; off <<= 1) {
        int y = __shfl_up(incl, off, 64);
        if (lane >= off) incl += y;
      }
      s_bb[b * NEXP + e] = running + (incl - v);
      running += __shfl(incl, 63, 64);
    }
    if (lane == 0) { s_cnt[e] = running; counts[e] = running; }
  }
  __syncthreads();

  if (tid == 0) {
    int a = 0, b2 = 0, g = 0;
#pragma unroll
    for (int e = 0; e < NEXP; ++e) {
      int c = s_cnt[e];
      int n1 = (c + 255) >> 8, n2 = (c + 127) >> 7;
      for (int i = 0; i < n1; ++i) t256[a++] = make_int4(e, i << 8, g + (i << 8), 0);
      for (int i = 0; i < n2; ++i) t128[b2++] = make_int4(e, i << 7, g + (i << 7), 0);
      g += n1 << 8;
    }
    nt[0] = a; nt[1] = b2;
  }

  for (int g = tid; g < NGRP; g += 1024) {
    int4 s0 = sel[g * 4 + 0], s1 = sel[g * 4 + 1];
    int4 s2 = sel[g * 4 + 2], s3 = sel[g * 4 + 3];
#define EMIT(i, sv, r0, r1)                                              \
    {                                                                     \
      int p0 = s_bb[g * NEXP + sv.x] + (r0);                              \
      int p1 = s_bb[g * NEXP + sv.y] + (r1);                              \
      idx_list[sv.x * N_TOK + p0] = g * 4 + i;                            \
      gate_list[sv.x * N_TOK + p0] = __int_as_float(sv.z);                \
      idx_list[sv.y * N_TOK + p1] = g * 4 + i;                            \
      gate_list[sv.y * N_TOK + p1] = __int_as_float(sv.w);                \
    }
    EMIT(0, s0, 0, 0);
    EMIT(1, s1, (s0.x == s1.x) + (s0.y == s1.x), (s0.x == s1.y) + (s0.y == s1.y));
    EMIT(2, s2, (s0.x == s2.x) + (s0.y == s2.x) + (s1.x == s2.x) + (s1.y == s2.x),
                (s0.x == s2.y) + (s0.y == s2.y) + (s1.x == s2.y) + (s1.y == s2.y));
    EMIT(3, s3, (s0.x == s3.x) + (s0.y == s3.x) + (s1.x == s3.x) + (s1.y == s3.x) +
                (s2.x == s3.x) + (s2.y == s3.x),
                (s0.x == s3.y) + (s0.y == s3.y) + (s1.x == s3.y) + (s1.y == s3.y) +
                (s2.x == s3.y) + (s2.y == s3.y));
#undef EMIT
  }
}

// ---------------- GEMM1: 256x256, BK=64, 8 waves, dbuf, 8-phase (r14) --------
// Equal to the 2-phase within noise; kept because it carries the fused w2-cvt
// at the measured-best granularity. Counted vmcnt(4) only at phases 4 & 8.
template <int TPX, int CW, bool FUSE>
__global__ __launch_bounds__(512, 1) void moe_g1_8p(
    const unsigned short* __restrict__ Abase, const unsigned short* __restrict__ Bb,
    unsigned short* __restrict__ Hout,
    const int* __restrict__ idx_list, const int* __restrict__ counts,
    const int4* __restrict__ table, const int* __restrict__ n_tiles,
    const float4* __restrict__ cvt_src, ushort4* __restrict__ cvt_dst) {
  constexpr int KDIM = DIM;
  int xcd, r0;
  if constexpr (FUSE) {
    const int bid = blockIdx.x;        // grid = 8 * 160
    xcd = bid & 7;
    const int r = bid >> 3;            // 0..159
    if (r % 10 == 9) {                 // 16 fat w2-cvt slots per XCD (128 total)
      const int c = xcd * 16 + r / 10;
      const int STR = 128 * 512;
      int i = c * 512 + (int)threadIdx.x;
      for (; i + 3 * STR < WN4; i += 4 * STR) {
        float4 f0 = cvt_src[i], f1 = cvt_src[i + STR];
        float4 f2 = cvt_src[i + 2 * STR], f3 = cvt_src[i + 3 * STR];
        cvt_dst[i] = bf4(f0); cvt_dst[i + STR] = bf4(f1);
        cvt_dst[i + 2 * STR] = bf4(f2); cvt_dst[i + 3 * STR] = bf4(f3);
      }
      for (; i < WN4; i += STR) cvt_dst[i] = bf4(cvt_src[i]);
      return;
    }
    r0 = r - r / 10;                   // 0..143
  } else {
    xcd = blockIdx.x & 7;
    r0 = blockIdx.x >> 3;              // grid 8*144
  }
  const int chunk = r0 / (TPX * CW), q = r0 % (TPX * CW);
  const int ty = xcd * TPX + q / CW;
  const int cx = chunk * CW + q % CW;
  if (ty >= *n_tiles) return;
  int4 te = table[ty];
  const int e = te.x, row_start = te.y, gbase = te.z;
  const int ce = counts[e];
  const int tid = threadIdx.x;
  const int wid = tid >> 6, lane = tid & 63;
  const int colT = cx * 256;

  extern __shared__ char smem[];       // A: 2x32768 @0, B: 2x32768 @65536

  const int sr = tid >> 3;
  const int scol = ((tid & 7) ^ (sr & 7)) * 8;
  size_t aoff[4], boff[4];
#pragma unroll
  for (int j = 0; j < 4; ++j) {
    int r = j * 64 + sr;
    int rl = row_start + r; if (rl >= ce) rl = ce - 1;
    int tok = idx_list[e * N_TOK + rl];
    aoff[j] = ((size_t)tok * KDIM + scol) * 2;
    boff[j] = ((size_t)e * FF * DIM + (size_t)(colT + r) * KDIM + scol) * 2;
  }
  const char* Ag = (const char*)Abase;
  const char* Bg = (const char*)Bb;

  auto stA = [&](int buf, int t, int h) {
    char* d = smem + buf * 32768 + h * 16384 + tid * 16;
    size_t ko = (size_t)t * 128;
    load_lds16(Ag + aoff[2 * h] + ko, d);
    load_lds16(Ag + aoff[2 * h + 1] + ko, d + 8192);
  };
  auto stB = [&](int buf, int t, int h) {
    char* d = smem + 65536 + buf * 32768 + h * 16384 + tid * 16;
    size_t ko = (size_t)t * 128;
    load_lds16(Bg + boff[2 * h] + ko, d);
    load_lds16(Bg + boff[2 * h + 1] + ko, d + 8192);
  };

  const int wr = wid >> 2, wc = wid & 3;         // 2x4 waves; wave out 128x64
  const int r16 = lane & 15, kg = lane >> 4;
  const int arow = (wr * 128 + r16) * 128;
  const int brow = (wc * 64 + r16) * 128;
  const int sof0 = (kg ^ (r16 & 7)) * 16;        // kf=0 slot
  const int sof1 = ((4 + kg) ^ (r16 & 7)) * 16;  // kf=1 slot

  f32x4 acc[8][4] = {};
  s16x8 bfr[4][2];

#define RDA(buf, m, kf) (*(const s16x8*)(smem + (buf)*32768 + arow + (m)*2048 + ((kf) ? sof1 : sof0)))
#define RDB(buf, n, kf) (*(const s16x8*)(smem + 65536 + (buf)*32768 + brow + (n)*2048 + ((kf) ? sof1 : sof0)))
#define MFMA_(a, b, c) __builtin_amdgcn_mfma_f32_16x16x32_bf16(a, b, c, 0, 0, 0)

  stA(0, 0, 0); stA(0, 0, 1); stB(0, 0, 0); stB(0, 0, 1);
  stB(1, 1, 0); stB(1, 1, 1);
  asm volatile("s_waitcnt vmcnt(4)" ::: "memory");
  asm volatile("s_barrier" ::: "memory");

#define PHASE(buf, mb, STAGE, TAIL)                                        \
  {                                                                         \
    s16x8 a00 = RDA(buf, mb, 0), a01 = RDA(buf, mb, 1);                     \
    s16x8 a10 = RDA(buf, mb + 1, 0), a11 = RDA(buf, mb + 1, 1);             \
    STAGE;                                                                  \
    asm volatile("s_barrier" ::: "memory");                                 \
    __builtin_amdgcn_s_setprio(1);                                          \
    _Pragma("unroll")                                                       \
    for (int n = 0; n < 4; ++n) {                                           \
      acc[mb][n] = MFMA_(a00, bfr[n][0], acc[mb][n]);                       \
      acc[mb][n] = MFMA_(a01, bfr[n][1], acc[mb][n]);                       \
      acc[mb + 1][n] = MFMA_(a10, bfr[n][0], acc[mb + 1][n]);               \
      acc[mb + 1][n] = MFMA_(a11, bfr[n][1], acc[mb + 1][n]);               \
    }                                                                       \
    __builtin_amdgcn_s_setprio(0);                                          \
    TAIL;                                                                   \
    asm volatile("s_barrier" ::: "memory");                                 \
  }

  for (int it = 0; it < KDIM / 128; ++it) {
    const int t0 = 2 * it;
    const bool nl = (it + 1 < KDIM / 128);
#pragma unroll
    for (int n = 0; n < 4; ++n) { bfr[n][0] = RDB(0, n, 0); bfr[n][1] = RDB(0, n, 1); }
    PHASE(0, 0, stA(1, t0 + 1, 0), (void)0);
    PHASE(0, 2, stA(1, t0 + 1, 1), (void)0);
    PHASE(0, 4, if (nl) stB(0, t0 + 2, 0), (void)0);
    PHASE(0, 6, if (nl) stB(0, t0 + 2, 1),
          if (nl) { asm volatile("s_waitcnt vmcnt(4)" ::: "memory"); }
          else    { asm volatile("s_waitcnt vmcnt(0)" ::: "memory"); });
#pragma unroll
    for (int n = 0; n < 4; ++n) { bfr[n][0] = RDB(1, n, 0); bfr[n][1] = RDB(1, n, 1); }
    PHASE(1, 0, if (nl) stA(0, t0 + 2, 0), (void)0);
    PHASE(1, 2, if (nl) stA(0, t0 + 2, 1), (void)0);
    PHASE(1, 4, if (nl) stB(1, t0 + 3, 0), (void)0);
    PHASE(1, 6, if (nl) stB(1, t0 + 3, 1),
          if (nl) { asm volatile("s_waitcnt vmcnt(4)" ::: "memory"); });
  }
#undef PHASE
#undef RDA
#undef RDB

#pragma unroll
  for (int m = 0; m < 8; ++m) {
    const int row_l = wr * 128 + m * 16 + kg * 4;
#pragma unroll
    for (int j = 0; j < 4; ++j) {
      size_t hrow = (size_t)(gbase + row_l + j) * FF + colT + wc * 64;
#pragma unroll
      for (int n = 0; n < 4; ++n)
        Hout[hrow + n * 16 + r16] = f2bf(gelu_f(acc[m][n][j]));
    }
  }
}

// ---------------- GEMM2: r13 kernel (proven), 128x128, BK=64, EPI=2 ----------
template <int KDIM, int EPI, int TPX, int CW>
__global__ __launch_bounds__(256, 4) void moe_g(
    const unsigned short* __restrict__ Abase, const unsigned short* __restrict__ Bb,
    unsigned short* __restrict__ Hout, float* __restrict__ Out,
    const int* __restrict__ idx_list, const float* __restrict__ gate_list,
    const int* __restrict__ counts, const int4* __restrict__ table,
    const int* __restrict__ n_tiles) {
  const int xcd = blockIdx.x & 7;
  const int r0 = blockIdx.x >> 3;
  const int chunk = r0 / (TPX * CW), q = r0 % (TPX * CW);
  const int ty = xcd * TPX + q / CW;
  const int cx = chunk * CW + q % CW;
  if (ty >= *n_tiles) return;
  int4 te = table[ty];
  const int e = te.x, row_start = te.y, gbase = te.z;
  const int ce = counts[e];
  const int tid = threadIdx.x;
  const int wid = tid >> 6, lane = tid & 63;
  const int colT = cx * 128;

  __shared__ unsigned short Al[128 * 64];
  __shared__ unsigned short Bl[128 * 64];

  const int sr = tid >> 3;
  const int scol = ((tid & 7) ^ (sr & 7)) * 8;
  size_t aoff[4], boff[4];
#pragma unroll
  for (int i = 0; i < 4; ++i) {
    int r = i * 32 + sr;
    if constexpr (EPI == 1) {
      int rl = row_start + r; if (rl >= ce) rl = ce - 1;
      int tok = idx_list[e * N_TOK + rl];
      aoff[i] = ((size_t)tok * KDIM + scol) * 2;
    } else {
      aoff[i] = ((size_t)(gbase + r) * KDIM + scol) * 2;
    }
    boff[i] = ((size_t)e * FF * DIM + (size_t)(colT + r) * KDIM + scol) * 2;
  }
  const char* Ag = (const char*)Abase;
  const char* Bg = (const char*)Bb;
  const int NT = KDIM / 64;

  const int wr = (wid >> 1) * 64, wc = (wid & 1) * 64;
  const int r16 = lane & 15, kg = lane >> 4;
  const int x7 = r16 & 7;

  f32x4 acc[4][4] = {};

  for (int t = 0; t < NT; ++t) {
    {
      char* da = (char*)Al + tid * 16;
      char* db = (char*)Bl + tid * 16;
      size_t ko = (size_t)t * 128;
#pragma unroll
      for (int i = 0; i < 4; ++i) load_lds16(Ag + aoff[i] + ko, da + i * 4096);
#pragma unroll
      for (int i = 0; i < 4; ++i) load_lds16(Bg + boff[i] + ko, db + i * 4096);
    }
    __syncthreads();
    const char* Ap = (const char*)Al + (wr + r16) * 128;
    const char* Bp = (const char*)Bl + (wc + r16) * 128;
#pragma unroll
    for (int kf = 0; kf < 2; ++kf) {
      const int so = ((kf * 4 + kg) ^ x7) * 16;
      s16x8 a[4], b[4];
#pragma unroll
      for (int m = 0; m < 4; ++m) a[m] = *(const s16x8*)(Ap + m * 2048 + so);
#pragma unroll
      for (int n = 0; n < 4; ++n) b[n] = *(const s16x8*)(Bp + n * 2048 + so);
#pragma unroll
      for (int m = 0; m < 4; ++m)
#pragma unroll
        for (int n = 0; n < 4; ++n)
          acc[m][n] = __builtin_amdgcn_mfma_f32_16x16x32_bf16(a[m], b[n], acc[m][n], 0, 0, 0);
    }
    __syncthreads();
  }

  if constexpr (EPI == 1) {
#pragma unroll
    for (int m = 0; m < 4; ++m) {
      const int row_l = wr + m * 16 + kg * 4;
#pragma unroll
      for (int j = 0; j < 4; ++j) {
        size_t hrow = (size_t)(gbase + row_l + j) * FF + colT + wc;
#pragma unroll
        for (int n = 0; n < 4; ++n)
          Hout[hrow + n * 16 + r16] = f2bf(gelu_f(acc[m][n][j]));
      }
    }
  } else {
#pragma unroll
    for (int m = 0; m < 4; ++m) {
      const int row_l = wr + m * 16 + kg * 4;
#pragma unroll
      for (int j = 0; j < 4; ++j) {
        int r = row_start + row_l + j;
        if (r < ce) {
          int tok = idx_list[e * N_TOK + r];
          float g = gate_list[e * N_TOK + r];
          float* orow = Out + (size_t)tok * DIM + colT + wc;
#pragma unroll
          for (int n = 0; n < 4; ++n)
            atomicAdd(&orow[n * 16 + r16], acc[m][n][j] * g);
        }
      }
    }
  }
}

// ---------------- launch ----------------
extern "C" void kernel_launch(void* const* d_in, const int* in_sizes, int n_in,
                              void* d_out, int out_size, void* d_ws, size_t ws_size,
                              hipStream_t stream) {
  const float* x  = (const float*)d_in[0];
  const float* rw = (const float*)d_in[1];
  const float* w1 = (const float*)d_in[2];
  const float* w2 = (const float*)d_in[3];
  float* out = (float*)d_out;
  char* ws = (char*)d_ws;
  if (ws_size < NEED) return;
  const bool sep = ws_size >= NEED2;

  int*   counts    = (int*)(ws + OFF_COUNTS);
  int*   nt        = (int*)(ws + OFF_NT);
  int4*  t256      = (int4*)(ws + OFF_T256);
  int4*  t128      = (int4*)(ws + OFF_T128);
  int*   idx_list  = (int*)(ws + OFF_IDX);
  float* gate_list = (float*)(ws + OFF_GATE);
  int*   bh        = (int*)(ws + OFF_BH);
  int4*  sel       = (int4*)(ws + OFF_SEL);
  unsigned short* xb  = (unsigned short*)(ws + OFF_XB);
  unsigned short* h   = (unsigned short*)(ws + OFF_H);
  unsigned short* wb  = (unsigned short*)(ws + OFF_WB);
  unsigned short* w2b = (unsigned short*)(ws + OFF_W2B);

  hipFuncSetAttribute(reinterpret_cast<const void*>(&scan_scatter),
                      hipFuncAttributeMaxDynamicSharedMemorySize, 65536);
  hipFuncSetAttribute(reinterpret_cast<const void*>(&moe_g1_8p<9, 8, true>),
                      hipFuncAttributeMaxDynamicSharedMemorySize, 131072);
  hipFuncSetAttribute(reinterpret_cast<const void*>(&moe_g1_8p<9, 8, false>),
                      hipFuncAttributeMaxDynamicSharedMemorySize, 131072);

  // K1: router (2048) + fat w1-cvt (256), 8:1 interleave
  router_cvt<<<2304, 256, 0, stream>>>(x, rw, bh, sel, xb,
                                       (const float4*)w1, (ushort4*)wb);
  // K2: scan + tables + scatter (block 0) + d_out zeroing (blocks 1..255)
  scan_scatter<<<256, 1024, 65536, stream>>>(bh, sel, counts, t256, t128, nt,
                                             idx_list, gate_list, (float4*)out);

  if (sep) {
    // GEMM1 8-phase: per-XCD 144 GEMM slots (9 ty x 16 cx, CW=8 chunks) + 16 cvt
    moe_g1_8p<9, 8, true><<<8 * 160, 512, 131072, stream>>>(
        xb, wb, h, idx_list, counts, t256, nt, (const float4*)w2, (ushort4*)w2b);
    moe_g<FF, 2, 17, 4><<<8 * MAXT, 256, 0, stream>>>(
        h, w2b, nullptr, out, idx_list, gate_list, counts, t128, nt + 1);
  } else {
    moe_g1_8p<9, 8, false><<<8 * 144, 512, 131072, stream>>>(
        xb, wb, h, idx_list, counts, t256, nt, nullptr, nullptr);
    cvt_f32_bf16<<<2048, 256, 0, stream>>>((const float4*)w2, (ushort4*)wb, WN4);
    moe_g<FF, 2, 17, 4><<<8 * MAXT, 256, 0, stream>>>(
        h, wb, nullptr, out, idx_list, gate_list, counts, t128, nt + 1);
  }
}